// Round 3
// baseline (800.950 us; speedup 1.0000x reference)
//
#include <hip/hip_runtime.h>
#include <hip/hip_bf16.h>

namespace {
constexpr int kB  = 8;
constexpr int kL  = 4096;
constexpr int kD  = 384;
constexpr int kNH = 8;
constexpr int kNP = 4;
constexpr int kHD = kD / kNH;   // 48
constexpr int kGW = 64;         // sqrt(kL)
constexpr int kM  = kB * kL;    // 32768 tokens
}

// -------------------------------------------------------------------------
// C[M,N] = A[M,K] @ W[K,N] + bias[N]; all f32, f32 accumulate.
// 64x64 block tile, BK=32, 256 threads, 4x4 register microtile.
// -------------------------------------------------------------------------
template<int BM, int BN, int BK>
__global__ __launch_bounds__(256)
void gemm_bias_kernel(const float* __restrict__ A, const float* __restrict__ W,
                      const float* __restrict__ bias, float* __restrict__ C,
                      int M, int N, int K)
{
  __shared__ float sA[BK][BM + 4];
  __shared__ float sB[BK][BN + 4];
  const int tid = threadIdx.x;
  const int nb  = N / BN;
  const int bm  = blockIdx.x / nb;
  const int bn  = blockIdx.x % nb;
  const int m0  = bm * BM, n0 = bn * BN;
  const int tn  = tid & 15, tm = tid >> 4;

  float acc[4][4] = {};

  for (int k0 = 0; k0 < K; k0 += BK) {
    {
      const int k  = tid & (BK - 1);     // 0..31
      const int mb = tid / BK;           // 0..7
      #pragma unroll
      for (int r = 0; r < BM / (256 / BK); ++r) {
        const int m = mb + r * (256 / BK);
        sA[k][m] = A[(size_t)(m0 + m) * K + (k0 + k)];
      }
    }
    {
      const int n  = tid & (BN - 1);     // 0..63
      const int kb = tid / BN;           // 0..3
      #pragma unroll
      for (int r = 0; r < BK / (256 / BN); ++r) {
        const int k = kb + r * (256 / BN);
        sB[k][n] = W[(size_t)(k0 + k) * N + (n0 + n)];
      }
    }
    __syncthreads();
    #pragma unroll
    for (int k = 0; k < BK; ++k) {
      float a[4], bb[4];
      #pragma unroll
      for (int i = 0; i < 4; ++i) a[i]  = sA[k][tm * 4 + i];
      #pragma unroll
      for (int j = 0; j < 4; ++j) bb[j] = sB[k][tn * 4 + j];
      #pragma unroll
      for (int i = 0; i < 4; ++i)
        #pragma unroll
        for (int j = 0; j < 4; ++j)
          acc[i][j] += a[i] * bb[j];
    }
    __syncthreads();
  }

  #pragma unroll
  for (int j = 0; j < 4; ++j) {
    const int n  = n0 + tn * 4 + j;
    const float bj = bias[n];
    #pragma unroll
    for (int i = 0; i < 4; ++i) {
      const int m = m0 + tm * 4 + i;
      C[(size_t)m * N + n] = acc[i][j] + bj;
    }
  }
}

// -------------------------------------------------------------------------
// Fused per-token: proj[96] = q.[Woff|Wwt]+[boff|bwt]; softmax per head over
// 4 point logits; bilinear sample v at clip(ref+off); weighted point sum.
// One 384-thread block per token. All f32.
// -------------------------------------------------------------------------
__global__ __launch_bounds__(384)
void deform_kernel(const float* __restrict__ query,
                   const float* __restrict__ Woff, const float* __restrict__ boff,
                   const float* __restrict__ Wwt,  const float* __restrict__ bwt,
                   const float* __restrict__ v,    float* __restrict__ agg)
{
  const int token = blockIdx.x;        // b*L + l
  const int b = token / kL;
  const int l = token % kL;
  const int t = threadIdx.x;           // 0..383

  __shared__ float q[kD];
  __shared__ float part[kD];
  __shared__ float proj[96];
  __shared__ int   sy0[32], sx0[32], sy1[32], sx1[32];
  __shared__ float swy[32], swx[32], swt[32];

  q[t] = query[(size_t)token * kD + t];
  __syncthreads();

  // 96 projections, K=384 split 4 ways over the block
  {
    const int j  = t % 96;
    const int kg = t / 96;             // 0..3
    float s = 0.f;
    if (j < 64) {
      const float* Wc = Woff + j;      // column j, stride 64
      for (int k = kg * 96; k < kg * 96 + 96; ++k)
        s += q[k] * Wc[(size_t)k * 64];
    } else {
      const float* Wc = Wwt + (j - 64); // column j-64, stride 32
      for (int k = kg * 96; k < kg * 96 + 96; ++k)
        s += q[k] * Wc[(size_t)k * 32];
    }
    part[t] = s;
  }
  __syncthreads();
  if (t < 96) {
    float s = part[t] + part[96 + t] + part[192 + t] + part[288 + t];
    s += (t < 64) ? boff[t] : bwt[t - 64];
    proj[t] = s;
  }
  __syncthreads();

  // coords per (h,p): i = h*4+p = t for t<32 ; off[h,p,c] = proj[2*i+c]
  if (t < 32) {
    const float offx = proj[2 * t];
    const float offy = proj[2 * t + 1];
    const float refx = (float)(l % kGW) * (1.0f / 63.0f);
    const float refy = (float)(l / kGW) * (1.0f / 63.0f);
    const float locx = fminf(fmaxf(refx + offx, 0.f), 1.f);
    const float locy = fminf(fmaxf(refy + offy, 0.f), 1.f);
    const float ph = locx * 63.0f;     // faithful: component 0 -> row coord
    const float pw = locy * 63.0f;
    const float fy = floorf(ph), fx = floorf(pw);
    const int y0 = (int)fy, x0 = (int)fx;
    sy0[t] = y0;               sx0[t] = x0;
    sy1[t] = min(y0 + 1, 63);  sx1[t] = min(x0 + 1, 63);
    swy[t] = ph - fy;          swx[t] = pw - fx;
  }
  // softmax per head: logits[h,p] = proj[64 + h*4 + p]
  if (t < 8) {
    const float* lg = proj + 64 + t * 4;
    const float m = fmaxf(fmaxf(lg[0], lg[1]), fmaxf(lg[2], lg[3]));
    float e[4], sum = 0.f;
    #pragma unroll
    for (int p = 0; p < 4; ++p) { e[p] = expf(lg[p] - m); sum += e[p]; }
    const float inv = 1.0f / sum;
    #pragma unroll
    for (int p = 0; p < 4; ++p) swt[t * 4 + p] = e[p] * inv;
  }
  __syncthreads();

  // gather + bilinear + weighted sum; t = h*48 + d
  const int h = t / kHD, d = t % kHD;
  const float* vb = v + (size_t)b * kL * kD + h * kHD + d;
  float acc = 0.f;
  #pragma unroll
  for (int p = 0; p < kNP; ++p) {
    const int i = h * kNP + p;
    const int y0 = sy0[i], x0 = sx0[i], y1 = sy1[i], x1 = sx1[i];
    const float wy = swy[i], wx = swx[i], w = swt[i];
    const float v00 = vb[(size_t)(y0 * kGW + x0) * kD];
    const float v01 = vb[(size_t)(y0 * kGW + x1) * kD];
    const float v10 = vb[(size_t)(y1 * kGW + x0) * kD];
    const float v11 = vb[(size_t)(y1 * kGW + x1) * kD];
    const float s = (1.f - wy) * ((1.f - wx) * v00 + wx * v01)
                  +        wy  * ((1.f - wx) * v10 + wx * v11);
    acc += w * s;
  }
  agg[(size_t)token * kD + t] = acc;
}

extern "C" void kernel_launch(void* const* d_in, const int* in_sizes, int n_in,
                              void* d_out, int out_size, void* d_ws, size_t ws_size,
                              hipStream_t stream)
{
  const float* query = (const float*)d_in[0];
  const float* value = (const float*)d_in[2];
  const float* Wv    = (const float*)d_in[7];
  const float* bv    = (const float*)d_in[8];
  const float* Woff  = (const float*)d_in[9];
  const float* boff  = (const float*)d_in[10];
  const float* Wwt   = (const float*)d_in[11];
  const float* bwt   = (const float*)d_in[12];
  const float* Wo    = (const float*)d_in[13];
  const float* bo    = (const float*)d_in[14];
  float* out = (float*)d_out;

  float* v_ws   = (float*)d_ws;                 // [kM, kD] f32
  float* agg_ws = v_ws + (size_t)kM * kD;       // [kM, kD] f32

  const dim3 gemm_grid((kM / 64) * (kD / 64));  // 3072 blocks

  // v = value @ Wv + bv
  gemm_bias_kernel<64, 64, 32><<<gemm_grid, 256, 0, stream>>>(
      value, Wv, bv, v_ws, kM, kD, kD);

  // proj + softmax + bilinear deformable sampling -> agg
  deform_kernel<<<dim3(kM), 384, 0, stream>>>(
      query, Woff, boff, Wwt, bwt, v_ws, agg_ws);

  // out = agg @ Wo + bo
  gemm_bias_kernel<64, 64, 32><<<gemm_grid, 256, 0, stream>>>(
      agg_ws, Wo, bo, out, kM, kD, kD);
}

// Round 4
// 339.309 us; speedup vs baseline: 2.3605x; 2.3605x over previous
//
#include <hip/hip_runtime.h>
#include <hip/hip_bf16.h>
#include <stdint.h>

using bf16 = __hip_bfloat16;

typedef __attribute__((ext_vector_type(8))) short short8;
typedef __attribute__((ext_vector_type(4))) float float4v;

namespace {
constexpr int kL  = 4096;
constexpr int kD  = 384;
constexpr int kNP = 4;
constexpr int kHD = 48;
constexpr int kGW = 64;
constexpr int kM  = 32768;

constexpr size_t nValue = (size_t)kM * kD;   // 12,582,912
constexpr size_t nW     = (size_t)kD * kD;   // 147,456
constexpr size_t nWcat  = (size_t)kD * 96;   // 36,864

// workspace offsets (bytes)
constexpr size_t oValB = 0;                                   // bf16 value  [kM][384]
constexpr size_t oWvt  = oValB + nValue * 2;                  // bf16 Wv^T   [384][384]
constexpr size_t oWot  = oWvt  + nW * 2;                      // bf16 Wo^T   [384][384]
constexpr size_t oWcat = oWot  + nW * 2;                      // f32 [384][96]
constexpr size_t oBcat = oWcat + nWcat * 4;                   // f32 [96]
constexpr size_t oVB   = (oBcat + 96 * 4 + 255) & ~size_t(255); // bf16 v [kM][384]
constexpr size_t oProj = oVB   + nValue * 2;                  // f32 [kM][96]
constexpr size_t oAgg  = oProj + (size_t)kM * 96 * 4;         // bf16 agg [kM][384]
}

__device__ __forceinline__ void load_lds_16(const void* g, void* l) {
  __builtin_amdgcn_global_load_lds((const __attribute__((address_space(1))) void*)g,
                                   (__attribute__((address_space(3))) void*)l,
                                   16, 0, 0);
}

// -------------------------------------------------------------------------
// prep: value f32->bf16; Wv,Wo transpose+cast to bf16 [n][k]; Woff|Wwt concat
// to f32 Wcat[384][96]; boff|bwt concat to bcat[96].
// -------------------------------------------------------------------------
__global__ void prep_kernel(const float* __restrict__ value,
                            const float* __restrict__ Wv,
                            const float* __restrict__ Wo,
                            const float* __restrict__ Woff,
                            const float* __restrict__ Wwt,
                            const float* __restrict__ boff,
                            const float* __restrict__ bwt,
                            bf16* __restrict__ valB, bf16* __restrict__ Wvt,
                            bf16* __restrict__ Wot,  float* __restrict__ Wcat,
                            float* __restrict__ bcat)
{
  size_t i = (size_t)blockIdx.x * 256 + threadIdx.x;
  if (i < nValue) { valB[i] = __float2bfloat16(value[i]); return; }
  i -= nValue;
  if (i < nW) {              // Wvt[n][k] = Wv[k][n]
    const int n = (int)(i / kD), k = (int)(i % kD);
    Wvt[i] = __float2bfloat16(Wv[(size_t)k * kD + n]);
    return;
  }
  i -= nW;
  if (i < nW) {
    const int n = (int)(i / kD), k = (int)(i % kD);
    Wot[i] = __float2bfloat16(Wo[(size_t)k * kD + n]);
    return;
  }
  i -= nW;
  if (i < nWcat) {           // Wcat[k][n], n<64 from Woff else Wwt
    const int k = (int)(i / 96), n = (int)(i % 96);
    Wcat[i] = (n < 64) ? Woff[(size_t)k * 64 + n] : Wwt[(size_t)k * 32 + (n - 64)];
    return;
  }
  i -= nWcat;
  if (i < 96) bcat[i] = (i < 64) ? boff[i] : bwt[i - 64];
}

// -------------------------------------------------------------------------
// MFMA bf16 GEMM: C[M,384] = A[M,384] @ B + bias, B given transposed as
// Bt[384][384] (Bt[n][k] = B[k][n]).  128x128 tile, BK=32, 256 threads,
// 4 waves each computing a 64x64 quadrant of 16x16x32 fragments.
// -------------------------------------------------------------------------
template<bool OUT_BF16>
__global__ __launch_bounds__(256)
void mfma_gemm_kernel(const bf16* __restrict__ A, const bf16* __restrict__ Bt,
                      const float* __restrict__ bias, void* __restrict__ Cout)
{
  __shared__ __align__(16) bf16 sA[128 * 32];
  __shared__ __align__(16) bf16 sB[128 * 32];
  const int tid  = threadIdx.x;
  const int lane = tid & 63;
  const int wave = tid >> 6;
  const int bm = blockIdx.x / 3, bn = blockIdx.x % 3;
  const int m0 = bm * 128, n0 = bn * 128;
  const int wm = (wave >> 1) * 64, wn = (wave & 1) * 64;
  const int r16 = lane & 15, quad = lane >> 4;

  float4v acc[4][4];
  #pragma unroll
  for (int i = 0; i < 4; ++i)
    #pragma unroll
    for (int j = 0; j < 4; ++j) acc[i][j] = (float4v){0.f, 0.f, 0.f, 0.f};

  const int c0 = tid, c1 = tid + 256;   // 16B-chunk ids (row = c>>2, koff = (c&3)*8)

  for (int kt = 0; kt < 12; ++kt) {
    const int k0 = kt * 32;
    load_lds_16(A  + (size_t)(m0 + (c0 >> 2)) * kD + k0 + (c0 & 3) * 8, (char*)sA + c0 * 16);
    load_lds_16(A  + (size_t)(m0 + (c1 >> 2)) * kD + k0 + (c1 & 3) * 8, (char*)sA + c1 * 16);
    load_lds_16(Bt + (size_t)(n0 + (c0 >> 2)) * kD + k0 + (c0 & 3) * 8, (char*)sB + c0 * 16);
    load_lds_16(Bt + (size_t)(n0 + (c1 >> 2)) * kD + k0 + (c1 & 3) * 8, (char*)sB + c1 * 16);
    __syncthreads();

    short8 av[4], bv[4];
    #pragma unroll
    for (int i = 0; i < 4; ++i)
      av[i] = *(const short8*)(sA + (wm + i * 16 + r16) * 32 + quad * 8);
    #pragma unroll
    for (int j = 0; j < 4; ++j)
      bv[j] = *(const short8*)(sB + (wn + j * 16 + r16) * 32 + quad * 8);
    #pragma unroll
    for (int i = 0; i < 4; ++i)
      #pragma unroll
      for (int j = 0; j < 4; ++j)
        acc[i][j] = __builtin_amdgcn_mfma_f32_16x16x32_bf16(av[i], bv[j], acc[i][j], 0, 0, 0);
    __syncthreads();
  }

  #pragma unroll
  for (int j = 0; j < 4; ++j) {
    const int col = n0 + wn + j * 16 + r16;
    const float bj = bias[col];
    #pragma unroll
    for (int i = 0; i < 4; ++i) {
      const int mbase = m0 + wm + i * 16 + quad * 4;
      #pragma unroll
      for (int r = 0; r < 4; ++r) {
        const float val = acc[i][j][r] + bj;
        if (OUT_BF16)
          ((bf16*)Cout)[(size_t)(mbase + r) * kD + col] = __float2bfloat16(val);
        else
          ((float*)Cout)[(size_t)(mbase + r) * kD + col] = val;
      }
    }
  }
}

// -------------------------------------------------------------------------
// f32 proj GEMM (coordinate path must stay f32):
// proj[M,96] = Q[M,384] @ Wcat[384,96] + bcat.  BM=64, BK=32, 256 threads,
// 4x6 microtile.
// -------------------------------------------------------------------------
__global__ __launch_bounds__(256)
void proj_gemm_kernel(const float* __restrict__ Q, const float* __restrict__ Wc,
                      const float* __restrict__ bc, float* __restrict__ proj)
{
  __shared__ float sA[32][65];    // [k][m]
  __shared__ float sB[32][100];   // [k][n]
  const int tid = threadIdx.x;
  const int m0  = blockIdx.x * 64;
  const int tm  = tid >> 4, tn = tid & 15;

  float acc[4][6] = {};

  for (int kt = 0; kt < 12; ++kt) {
    const int k0 = kt * 32;
    #pragma unroll
    for (int r = 0; r < 8; ++r) {          // 64x32 A tile
      const int e = tid + r * 256;
      const int m = e >> 5, k = e & 31;
      sA[k][m] = Q[(size_t)(m0 + m) * kD + k0 + k];
    }
    #pragma unroll
    for (int r = 0; r < 12; ++r) {         // 32x96 B tile
      const int e = tid + r * 256;
      const int k = e / 96, n = e % 96;
      sB[k][n] = Wc[(size_t)(k0 + k) * 96 + n];
    }
    __syncthreads();
    #pragma unroll
    for (int k = 0; k < 32; ++k) {
      float a[4], b[6];
      #pragma unroll
      for (int i = 0; i < 4; ++i) a[i] = sA[k][tm * 4 + i];
      #pragma unroll
      for (int j = 0; j < 6; ++j) b[j] = sB[k][tn * 6 + j];
      #pragma unroll
      for (int i = 0; i < 4; ++i)
        #pragma unroll
        for (int j = 0; j < 6; ++j)
          acc[i][j] += a[i] * b[j];
    }
    __syncthreads();
  }

  #pragma unroll
  for (int j = 0; j < 6; ++j) {
    const int col = tn * 6 + j;
    const float bj = bc[col];
    #pragma unroll
    for (int i = 0; i < 4; ++i)
      proj[(size_t)(m0 + tm * 4 + i) * 96 + col] = acc[i][j] + bj;
  }
}

// -------------------------------------------------------------------------
// Sampling: coords+softmax from proj (f32), bilinear gather from v (bf16),
// weighted point sum -> agg (bf16). One 384-thread block per token.
// -------------------------------------------------------------------------
__global__ __launch_bounds__(384)
void sample_kernel(const float* __restrict__ proj, const bf16* __restrict__ v,
                   bf16* __restrict__ agg)
{
  const int token = blockIdx.x;
  const int b = token / kL;
  const int l = token % kL;
  const int t = threadIdx.x;

  __shared__ float sp[96];
  __shared__ int   sy0[32], sx0[32], sy1[32], sx1[32];
  __shared__ float swy[32], swx[32], swt[32];

  if (t < 96) sp[t] = proj[(size_t)token * 96 + t];
  __syncthreads();

  if (t < 32) {
    const float offx = sp[2 * t];
    const float offy = sp[2 * t + 1];
    const float refx = (float)(l % kGW) * (1.0f / 63.0f);
    const float refy = (float)(l / kGW) * (1.0f / 63.0f);
    const float locx = fminf(fmaxf(refx + offx, 0.f), 1.f);
    const float locy = fminf(fmaxf(refy + offy, 0.f), 1.f);
    const float ph = locx * 63.0f;   // faithful: component 0 -> row coord
    const float pw = locy * 63.0f;
    const float fy = floorf(ph), fx = floorf(pw);
    const int y0 = (int)fy, x0 = (int)fx;
    sy0[t] = y0;               sx0[t] = x0;
    sy1[t] = min(y0 + 1, 63);  sx1[t] = min(x0 + 1, 63);
    swy[t] = ph - fy;          swx[t] = pw - fx;
  }
  if (t < 8) {
    const float* lg = sp + 64 + t * 4;
    const float m = fmaxf(fmaxf(lg[0], lg[1]), fmaxf(lg[2], lg[3]));
    float e[4], sum = 0.f;
    #pragma unroll
    for (int p = 0; p < 4; ++p) { e[p] = expf(lg[p] - m); sum += e[p]; }
    const float inv = 1.0f / sum;
    #pragma unroll
    for (int p = 0; p < 4; ++p) swt[t * 4 + p] = e[p] * inv;
  }
  __syncthreads();

  const int h = t / kHD, d = t % kHD;
  const bf16* vb = v + (size_t)b * kL * kD + h * kHD + d;
  float acc = 0.f;
  #pragma unroll
  for (int p = 0; p < kNP; ++p) {
    const int i = h * kNP + p;
    const int y0 = sy0[i], x0 = sx0[i], y1 = sy1[i], x1 = sx1[i];
    const float wy = swy[i], wx = swx[i], w = swt[i];
    const float v00 = __bfloat162float(vb[(size_t)(y0 * kGW + x0) * kD]);
    const float v01 = __bfloat162float(vb[(size_t)(y0 * kGW + x1) * kD]);
    const float v10 = __bfloat162float(vb[(size_t)(y1 * kGW + x0) * kD]);
    const float v11 = __bfloat162float(vb[(size_t)(y1 * kGW + x1) * kD]);
    const float s = (1.f - wy) * ((1.f - wx) * v00 + wx * v01)
                  +        wy  * ((1.f - wx) * v10 + wx * v11);
    acc += w * s;
  }
  agg[(size_t)token * kD + t] = __float2bfloat16(acc);
}

extern "C" void kernel_launch(void* const* d_in, const int* in_sizes, int n_in,
                              void* d_out, int out_size, void* d_ws, size_t ws_size,
                              hipStream_t stream)
{
  const float* query = (const float*)d_in[0];
  const float* value = (const float*)d_in[2];
  const float* Wv    = (const float*)d_in[7];
  const float* bv    = (const float*)d_in[8];
  const float* Woff  = (const float*)d_in[9];
  const float* boff  = (const float*)d_in[10];
  const float* Wwt   = (const float*)d_in[11];
  const float* bwt   = (const float*)d_in[12];
  const float* Wo    = (const float*)d_in[13];
  const float* bo    = (const float*)d_in[14];
  float* out = (float*)d_out;

  char* ws = (char*)d_ws;
  bf16*  valB = (bf16*)(ws + oValB);
  bf16*  Wvt  = (bf16*)(ws + oWvt);
  bf16*  Wot  = (bf16*)(ws + oWot);
  float* Wcat = (float*)(ws + oWcat);
  float* bcat = (float*)(ws + oBcat);
  bf16*  vB   = (bf16*)(ws + oVB);
  float* proj = (float*)(ws + oProj);
  bf16*  aggB = (bf16*)(ws + oAgg);

  const size_t prepN = nValue + nW + nW + nWcat + 96;
  prep_kernel<<<dim3((unsigned)((prepN + 255) / 256)), 256, 0, stream>>>(
      value, Wv, Wo, Woff, Wwt, boff, bwt, valB, Wvt, Wot, Wcat, bcat);

  // v = value @ Wv + bv  (bf16 MFMA, bf16 out)
  mfma_gemm_kernel<true><<<dim3((kM / 128) * 3), 256, 0, stream>>>(
      valB, Wvt, bv, vB);

  // proj = query @ [Woff|Wwt] + [boff|bwt]  (f32 — coordinate precision)
  proj_gemm_kernel<<<dim3(kM / 64), 256, 0, stream>>>(query, Wcat, bcat, proj);

  // coords + softmax + bilinear gather -> agg (bf16)
  sample_kernel<<<dim3(kM), 384, 0, stream>>>(proj, vB, aggB);

  // out = agg @ Wo + bo  (bf16 MFMA, f32 out)
  mfma_gemm_kernel<false><<<dim3((kM / 128) * 3), 256, 0, stream>>>(
      aggB, Wot, bo, out);
}

// Round 5
// 305.984 us; speedup vs baseline: 2.6176x; 1.1089x over previous
//
#include <hip/hip_runtime.h>
#include <hip/hip_bf16.h>
#include <stdint.h>

using bf16 = __hip_bfloat16;

typedef __attribute__((ext_vector_type(8))) short short8;
typedef __attribute__((ext_vector_type(4))) float float4v;

namespace {
constexpr int kL  = 4096;
constexpr int kD  = 384;
constexpr int kNP = 4;
constexpr int kHD = 48;
constexpr int kGW = 64;
constexpr int kM  = 32768;

constexpr size_t nValue = (size_t)kM * kD;   // 12,582,912
constexpr size_t nW     = (size_t)kD * kD;   // 147,456
constexpr size_t nWcat  = (size_t)kD * 96;   // 36,864

// workspace offsets (bytes)
constexpr size_t oWvt  = 0;                                    // bf16 Wv^T [384][384]
constexpr size_t oWot  = oWvt  + nW * 2;                       // bf16 Wo^T [384][384]
constexpr size_t oWcat = oWot  + nW * 2;                       // f32 [384][96]
constexpr size_t oBcat = oWcat + nWcat * 4;                    // f32 [96]
constexpr size_t oVB   = (oBcat + 96 * 4 + 255) & ~size_t(255);// bf16 v [kM][384]
constexpr size_t oProj = oVB   + nValue * 2;                   // f32 [kM][96]
constexpr size_t oAgg  = oProj + (size_t)kM * 96 * 4;          // bf16 agg [kM][384]
}

__device__ __forceinline__ void load_lds_16(const void* g, void* l) {
  __builtin_amdgcn_global_load_lds((const __attribute__((address_space(1))) void*)g,
                                   (__attribute__((address_space(3))) void*)l,
                                   16, 0, 0);
}

__device__ __forceinline__ short bf16bits(float f) {
  bf16 h = __float2bfloat16(f);
  return *reinterpret_cast<short*>(&h);
}

// -------------------------------------------------------------------------
// prep (weights only): Wv,Wo transpose+cast to bf16 [n][k]; Woff|Wwt concat
// to f32 Wcat[384][96]; boff|bwt concat to bcat[96].
// -------------------------------------------------------------------------
__global__ void prep_kernel(const float* __restrict__ Wv,
                            const float* __restrict__ Wo,
                            const float* __restrict__ Woff,
                            const float* __restrict__ Wwt,
                            const float* __restrict__ boff,
                            const float* __restrict__ bwt,
                            bf16* __restrict__ Wvt, bf16* __restrict__ Wot,
                            float* __restrict__ Wcat, float* __restrict__ bcat)
{
  size_t i = (size_t)blockIdx.x * 256 + threadIdx.x;
  if (i < nW) {              // Wvt[n][k] = Wv[k][n]
    const int n = (int)(i / kD), k = (int)(i % kD);
    Wvt[i] = __float2bfloat16(Wv[(size_t)k * kD + n]);
    return;
  }
  i -= nW;
  if (i < nW) {
    const int n = (int)(i / kD), k = (int)(i % kD);
    Wot[i] = __float2bfloat16(Wo[(size_t)k * kD + n]);
    return;
  }
  i -= nW;
  if (i < nWcat) {           // Wcat[k][n], n<64 from Woff else Wwt
    const int k = (int)(i / 96), n = (int)(i % 96);
    Wcat[i] = (n < 64) ? Woff[(size_t)k * 64 + n] : Wwt[(size_t)k * 32 + (n - 64)];
    return;
  }
  i -= nWcat;
  if (i < 96) bcat[i] = (i < 64) ? boff[i] : bwt[i - 64];
}

// -------------------------------------------------------------------------
// MFMA bf16 GEMM: C[M,384] = A[M,384] @ B + bias, B transposed (Bt[n][k]).
// 128x128 tile, BK=32, 256 threads, 4 waves x (64x64 quadrant of 16x16x32).
// A_F32: A is f32, converted to bf16 during LDS staging (fused cast).
// -------------------------------------------------------------------------
template<bool A_F32, bool OUT_BF16>
__global__ __launch_bounds__(256)
void mfma_gemm_kernel(const void* __restrict__ A, const bf16* __restrict__ Bt,
                      const float* __restrict__ bias, void* __restrict__ Cout)
{
  __shared__ __align__(16) bf16 sA[128 * 32];
  __shared__ __align__(16) bf16 sB[128 * 32];
  const int tid  = threadIdx.x;
  const int lane = tid & 63;
  const int wave = tid >> 6;
  const int bm = blockIdx.x / 3, bn = blockIdx.x % 3;
  const int m0 = bm * 128, n0 = bn * 128;
  const int wm = (wave >> 1) * 64, wn = (wave & 1) * 64;
  const int r16 = lane & 15, quad = lane >> 4;

  float4v acc[4][4];
  #pragma unroll
  for (int i = 0; i < 4; ++i)
    #pragma unroll
    for (int j = 0; j < 4; ++j) acc[i][j] = (float4v){0.f, 0.f, 0.f, 0.f};

  const int c0 = tid, c1 = tid + 256;   // 16B chunks: row = c>>2, koff = (c&3)*8

  for (int kt = 0; kt < 12; ++kt) {
    const int k0 = kt * 32;
    if (A_F32) {
      const float* Af = (const float*)A;
      #pragma unroll
      for (int r = 0; r < 2; ++r) {
        const int e = tid + r * 256;
        const int row = e >> 2, c = e & 3;
        const float* src = Af + (size_t)(m0 + row) * kD + k0 + c * 8;
        const float4 f0 = *(const float4*)src;
        const float4 f1 = *(const float4*)(src + 4);
        short8 hx;
        hx[0] = bf16bits(f0.x); hx[1] = bf16bits(f0.y);
        hx[2] = bf16bits(f0.z); hx[3] = bf16bits(f0.w);
        hx[4] = bf16bits(f1.x); hx[5] = bf16bits(f1.y);
        hx[6] = bf16bits(f1.z); hx[7] = bf16bits(f1.w);
        *(short8*)((char*)sA + e * 16) = hx;
      }
    } else {
      const bf16* Ab = (const bf16*)A;
      load_lds_16(Ab + (size_t)(m0 + (c0 >> 2)) * kD + k0 + (c0 & 3) * 8, (char*)sA + c0 * 16);
      load_lds_16(Ab + (size_t)(m0 + (c1 >> 2)) * kD + k0 + (c1 & 3) * 8, (char*)sA + c1 * 16);
    }
    load_lds_16(Bt + (size_t)(n0 + (c0 >> 2)) * kD + k0 + (c0 & 3) * 8, (char*)sB + c0 * 16);
    load_lds_16(Bt + (size_t)(n0 + (c1 >> 2)) * kD + k0 + (c1 & 3) * 8, (char*)sB + c1 * 16);
    __syncthreads();

    short8 av[4], bv[4];
    #pragma unroll
    for (int i = 0; i < 4; ++i)
      av[i] = *(const short8*)(sA + (wm + i * 16 + r16) * 32 + quad * 8);
    #pragma unroll
    for (int j = 0; j < 4; ++j)
      bv[j] = *(const short8*)(sB + (wn + j * 16 + r16) * 32 + quad * 8);
    #pragma unroll
    for (int i = 0; i < 4; ++i)
      #pragma unroll
      for (int j = 0; j < 4; ++j)
        acc[i][j] = __builtin_amdgcn_mfma_f32_16x16x32_bf16(av[i], bv[j], acc[i][j], 0, 0, 0);
    __syncthreads();
  }

  #pragma unroll
  for (int j = 0; j < 4; ++j) {
    const int col = n0 + wn + j * 16 + r16;
    const float bj = bias[col];
    #pragma unroll
    for (int i = 0; i < 4; ++i) {
      const int mbase = m0 + wm + i * 16 + quad * 4;
      #pragma unroll
      for (int r = 0; r < 4; ++r) {
        const float val = acc[i][j][r] + bj;
        if (OUT_BF16)
          ((bf16*)Cout)[(size_t)(mbase + r) * kD + col] = __float2bfloat16(val);
        else
          ((float*)Cout)[(size_t)(mbase + r) * kD + col] = val;
      }
    }
  }
}

// -------------------------------------------------------------------------
// f32 proj GEMM (coordinate path stays f32):
// proj[M,96] = Q[M,384] @ Wcat[384,96] + bcat. BM=64, BK=32, 256 threads,
// 4x6 microtile; vectorized LDS (b128 a-read, 3x b64 b-read).
// -------------------------------------------------------------------------
__global__ __launch_bounds__(256)
void proj_gemm_kernel(const float* __restrict__ Q, const float* __restrict__ Wc,
                      const float* __restrict__ bc, float* __restrict__ proj)
{
  __shared__ float sA[32][68];    // [k][m], row = 272B (16B-aligned)
  __shared__ float sB[32][100];   // [k][n], row = 400B (16B-aligned)
  const int tid = threadIdx.x;
  const int m0  = blockIdx.x * 64;
  const int tm  = tid >> 4, tn = tid & 15;

  float acc[4][6] = {};

  for (int kt = 0; kt < 12; ++kt) {
    const int k0 = kt * 32;
    // A tile 64x32 f32: 512 float4 chunks; m = e>>3, kc = e&7 (transpose in regs)
    #pragma unroll
    for (int r = 0; r < 2; ++r) {
      const int e = tid + r * 256;
      const int m = e >> 3, kc = e & 7;
      const float4 f = *(const float4*)(Q + (size_t)(m0 + m) * kD + k0 + kc * 4);
      sA[kc * 4 + 0][m] = f.x;
      sA[kc * 4 + 1][m] = f.y;
      sA[kc * 4 + 2][m] = f.z;
      sA[kc * 4 + 3][m] = f.w;
    }
    // B tile 32x96 f32: 1536 float2 chunks; k = e/48, n2 = (e%48)*2
    #pragma unroll
    for (int r = 0; r < 6; ++r) {
      const int e = tid + r * 256;
      const int k = e / 48, n2 = (e % 48) * 2;
      *(float2*)(&sB[k][n2]) = *(const float2*)(Wc + (size_t)(k0 + k) * 96 + n2);
    }
    __syncthreads();
    #pragma unroll
    for (int k = 0; k < 32; ++k) {
      const float4 a  = *(const float4*)(&sA[k][tm * 4]);
      const float2 b0 = *(const float2*)(&sB[k][tn * 6]);
      const float2 b1 = *(const float2*)(&sB[k][tn * 6 + 2]);
      const float2 b2 = *(const float2*)(&sB[k][tn * 6 + 4]);
      const float av[4] = {a.x, a.y, a.z, a.w};
      const float bb[6] = {b0.x, b0.y, b1.x, b1.y, b2.x, b2.y};
      #pragma unroll
      for (int i = 0; i < 4; ++i)
        #pragma unroll
        for (int j = 0; j < 6; ++j)
          acc[i][j] += av[i] * bb[j];
    }
    __syncthreads();
  }

  #pragma unroll
  for (int j = 0; j < 6; ++j) {
    const int col = tn * 6 + j;
    const float bj = bc[col];
    #pragma unroll
    for (int i = 0; i < 4; ++i)
      proj[(size_t)(m0 + tm * 4 + i) * 96 + col] = acc[i][j] + bj;
  }
}

// -------------------------------------------------------------------------
// Sampling: coords+softmax from proj (f32), bilinear gather from v (bf16),
// weighted point sum -> agg (bf16). One 384-thread block per token.
// XCD swizzle: XCD x (blockIdx%8) handles only batch x -> v slice (3.1 MB)
// stays resident in that XCD's 4 MB L2.
// -------------------------------------------------------------------------
__global__ __launch_bounds__(384)
void sample_kernel(const float* __restrict__ proj, const bf16* __restrict__ v,
                   bf16* __restrict__ agg)
{
  const int b = blockIdx.x & 7;
  const int l = blockIdx.x >> 3;
  const int token = b * kL + l;
  const int t = threadIdx.x;

  __shared__ float sp[96];
  __shared__ int   sy0[32], sx0[32], sy1[32], sx1[32];
  __shared__ float swy[32], swx[32], swt[32];

  if (t < 96) sp[t] = proj[(size_t)token * 96 + t];
  __syncthreads();

  if (t < 32) {
    const float offx = sp[2 * t];
    const float offy = sp[2 * t + 1];
    const float refx = (float)(l % kGW) * (1.0f / 63.0f);
    const float refy = (float)(l / kGW) * (1.0f / 63.0f);
    const float locx = fminf(fmaxf(refx + offx, 0.f), 1.f);
    const float locy = fminf(fmaxf(refy + offy, 0.f), 1.f);
    const float ph = locx * 63.0f;   // faithful: component 0 -> row coord
    const float pw = locy * 63.0f;
    const float fy = floorf(ph), fx = floorf(pw);
    const int y0 = (int)fy, x0 = (int)fx;
    sy0[t] = y0;               sx0[t] = x0;
    sy1[t] = min(y0 + 1, 63);  sx1[t] = min(x0 + 1, 63);
    swy[t] = ph - fy;          swx[t] = pw - fx;
  }
  if (t < 8) {
    const float* lg = sp + 64 + t * 4;
    const float m = fmaxf(fmaxf(lg[0], lg[1]), fmaxf(lg[2], lg[3]));
    float e[4], sum = 0.f;
    #pragma unroll
    for (int p = 0; p < 4; ++p) { e[p] = expf(lg[p] - m); sum += e[p]; }
    const float inv = 1.0f / sum;
    #pragma unroll
    for (int p = 0; p < 4; ++p) swt[t * 4 + p] = e[p] * inv;
  }
  __syncthreads();

  const int h = t / kHD, d = t % kHD;
  const bf16* vb = v + (size_t)b * kL * kD + h * kHD + d;
  float acc = 0.f;
  #pragma unroll
  for (int p = 0; p < kNP; ++p) {
    const int i = h * kNP + p;
    const int y0 = sy0[i], x0 = sx0[i], y1 = sy1[i], x1 = sx1[i];
    const float wy = swy[i], wx = swx[i], w = swt[i];
    const float v00 = __bfloat162float(vb[(size_t)(y0 * kGW + x0) * kD]);
    const float v01 = __bfloat162float(vb[(size_t)(y0 * kGW + x1) * kD]);
    const float v10 = __bfloat162float(vb[(size_t)(y1 * kGW + x0) * kD]);
    const float v11 = __bfloat162float(vb[(size_t)(y1 * kGW + x1) * kD]);
    const float s = (1.f - wy) * ((1.f - wx) * v00 + wx * v01)
                  +        wy  * ((1.f - wx) * v10 + wx * v11);
    acc += w * s;
  }
  agg[(size_t)token * kD + t] = __float2bfloat16(acc);
}

extern "C" void kernel_launch(void* const* d_in, const int* in_sizes, int n_in,
                              void* d_out, int out_size, void* d_ws, size_t ws_size,
                              hipStream_t stream)
{
  const float* query = (const float*)d_in[0];
  const float* value = (const float*)d_in[2];
  const float* Wv    = (const float*)d_in[7];
  const float* bv    = (const float*)d_in[8];
  const float* Woff  = (const float*)d_in[9];
  const float* boff  = (const float*)d_in[10];
  const float* Wwt   = (const float*)d_in[11];
  const float* bwt   = (const float*)d_in[12];
  const float* Wo    = (const float*)d_in[13];
  const float* bo    = (const float*)d_in[14];
  float* out = (float*)d_out;

  char* ws = (char*)d_ws;
  bf16*  Wvt  = (bf16*)(ws + oWvt);
  bf16*  Wot  = (bf16*)(ws + oWot);
  float* Wcat = (float*)(ws + oWcat);
  float* bcat = (float*)(ws + oBcat);
  bf16*  vB   = (bf16*)(ws + oVB);
  float* proj = (float*)(ws + oProj);
  bf16*  aggB = (bf16*)(ws + oAgg);

  const size_t prepN = nW + nW + nWcat + 96;
  prep_kernel<<<dim3((unsigned)((prepN + 255) / 256)), 256, 0, stream>>>(
      Wv, Wo, Woff, Wwt, boff, bwt, Wvt, Wot, Wcat, bcat);

  // v = value @ Wv + bv  (f32 A with fused cast, bf16 MFMA, bf16 out)
  mfma_gemm_kernel<true, true><<<dim3((kM / 128) * 3), 256, 0, stream>>>(
      value, Wvt, bv, vB);

  // proj = query @ [Woff|Wwt] + [boff|bwt]  (f32 — coordinate precision)
  proj_gemm_kernel<<<dim3(kM / 64), 256, 0, stream>>>(query, Wcat, bcat, proj);

  // coords + softmax + bilinear gather -> agg (bf16)
  sample_kernel<<<dim3(kM), 384, 0, stream>>>(proj, vB, aggB);

  // out = agg @ Wo + bo  (bf16 MFMA, f32 out)
  mfma_gemm_kernel<false, false><<<dim3((kM / 128) * 3), 256, 0, stream>>>(
      aggB, Wot, bo, out);
}

// Round 6
// 294.694 us; speedup vs baseline: 2.7179x; 1.0383x over previous
//
#include <hip/hip_runtime.h>
#include <hip/hip_bf16.h>
#include <stdint.h>

using bf16 = __hip_bfloat16;

typedef __attribute__((ext_vector_type(8))) short short8;
typedef __attribute__((ext_vector_type(4))) float float4v;

namespace {
constexpr int kL  = 4096;
constexpr int kD  = 384;
constexpr int kHD = 48;
constexpr int kGW = 64;
constexpr int kM  = 32768;

constexpr size_t nValue = (size_t)kM * kD;
constexpr size_t nW     = (size_t)kD * kD;
constexpr size_t nWcat  = (size_t)kD * 96;

// workspace offsets (bytes)
constexpr size_t oWvt  = 0;                                    // bf16 Wv^T [384][384]
constexpr size_t oWot  = oWvt  + nW * 2;                       // bf16 Wo^T [384][384]
constexpr size_t oWcat = oWot  + nW * 2;                       // f32 [384][96]
constexpr size_t oBcat = oWcat + nWcat * 4;                    // f32 [96]
constexpr size_t oVB   = (oBcat + 96 * 4 + 255) & ~size_t(255);// bf16 v [kM][384]
constexpr size_t oProj = oVB   + nValue * 2;                   // f32 [kM][96]
constexpr size_t oAgg  = oProj + (size_t)kM * 96 * 4;          // bf16 agg [kM][384]
}

__device__ __forceinline__ void load_lds_16(const void* g, void* l) {
  __builtin_amdgcn_global_load_lds((const __attribute__((address_space(1))) void*)g,
                                   (__attribute__((address_space(3))) void*)l,
                                   16, 0, 0);
}

__device__ __forceinline__ short bf16bits(float f) {
  bf16 h = __float2bfloat16(f);
  return *reinterpret_cast<short*>(&h);
}

__device__ __forceinline__ float bf16raw2f(unsigned short u) {
  union { unsigned int i; float f; } c;
  c.i = ((unsigned int)u) << 16;
  return c.f;
}

// -------------------------------------------------------------------------
// prep (weights only)
// -------------------------------------------------------------------------
__global__ void prep_kernel(const float* __restrict__ Wv,
                            const float* __restrict__ Wo,
                            const float* __restrict__ Woff,
                            const float* __restrict__ Wwt,
                            const float* __restrict__ boff,
                            const float* __restrict__ bwt,
                            bf16* __restrict__ Wvt, bf16* __restrict__ Wot,
                            float* __restrict__ Wcat, float* __restrict__ bcat)
{
  size_t i = (size_t)blockIdx.x * 256 + threadIdx.x;
  if (i < nW) {
    const int n = (int)(i / kD), k = (int)(i % kD);
    Wvt[i] = __float2bfloat16(Wv[(size_t)k * kD + n]);
    return;
  }
  i -= nW;
  if (i < nW) {
    const int n = (int)(i / kD), k = (int)(i % kD);
    Wot[i] = __float2bfloat16(Wo[(size_t)k * kD + n]);
    return;
  }
  i -= nW;
  if (i < nWcat) {
    const int k = (int)(i / 96), n = (int)(i % 96);
    Wcat[i] = (n < 64) ? Woff[(size_t)k * 64 + n] : Wwt[(size_t)k * 32 + (n - 64)];
    return;
  }
  i -= nWcat;
  if (i < 96) bcat[i] = (i < 64) ? boff[i] : bwt[i - 64];
}

// -------------------------------------------------------------------------
// MFMA GEMM body (device): C[M,384] = A @ B + bias, Bt[n][k] bf16.
// 128x128 tile, BK=32, 256 threads, 4 waves. A_F32 -> fused cast staging.
// -------------------------------------------------------------------------
template<bool A_F32, bool OUT_BF16>
__device__ __forceinline__
void mfma_gemm_body(char* smem, int bid,
                    const void* __restrict__ A, const bf16* __restrict__ Bt,
                    const float* __restrict__ bias, void* __restrict__ Cout)
{
  bf16* sA = (bf16*)smem;            // 128*32 bf16 = 8 KB
  bf16* sB = (bf16*)(smem + 8192);   // 8 KB
  const int tid  = threadIdx.x;
  const int lane = tid & 63;
  const int wave = tid >> 6;
  const int bm = bid / 3, bn = bid % 3;
  const int m0 = bm * 128, n0 = bn * 128;
  const int wm = (wave >> 1) * 64, wn = (wave & 1) * 64;
  const int r16 = lane & 15, quad = lane >> 4;

  float4v acc[4][4];
  #pragma unroll
  for (int i = 0; i < 4; ++i)
    #pragma unroll
    for (int j = 0; j < 4; ++j) acc[i][j] = (float4v){0.f, 0.f, 0.f, 0.f};

  const int c0 = tid, c1 = tid + 256;

  for (int kt = 0; kt < 12; ++kt) {
    const int k0 = kt * 32;
    if (A_F32) {
      const float* Af = (const float*)A;
      #pragma unroll
      for (int r = 0; r < 2; ++r) {
        const int e = tid + r * 256;
        const int row = e >> 2, c = e & 3;
        const float* src = Af + (size_t)(m0 + row) * kD + k0 + c * 8;
        const float4 f0 = *(const float4*)src;
        const float4 f1 = *(const float4*)(src + 4);
        short8 hx;
        hx[0] = bf16bits(f0.x); hx[1] = bf16bits(f0.y);
        hx[2] = bf16bits(f0.z); hx[3] = bf16bits(f0.w);
        hx[4] = bf16bits(f1.x); hx[5] = bf16bits(f1.y);
        hx[6] = bf16bits(f1.z); hx[7] = bf16bits(f1.w);
        *(short8*)((char*)sA + e * 16) = hx;
      }
    } else {
      const bf16* Ab = (const bf16*)A;
      load_lds_16(Ab + (size_t)(m0 + (c0 >> 2)) * kD + k0 + (c0 & 3) * 8, (char*)sA + c0 * 16);
      load_lds_16(Ab + (size_t)(m0 + (c1 >> 2)) * kD + k0 + (c1 & 3) * 8, (char*)sA + c1 * 16);
    }
    load_lds_16(Bt + (size_t)(n0 + (c0 >> 2)) * kD + k0 + (c0 & 3) * 8, (char*)sB + c0 * 16);
    load_lds_16(Bt + (size_t)(n0 + (c1 >> 2)) * kD + k0 + (c1 & 3) * 8, (char*)sB + c1 * 16);
    __syncthreads();

    short8 av[4], bv[4];
    #pragma unroll
    for (int i = 0; i < 4; ++i)
      av[i] = *(const short8*)(sA + (wm + i * 16 + r16) * 32 + quad * 8);
    #pragma unroll
    for (int j = 0; j < 4; ++j)
      bv[j] = *(const short8*)(sB + (wn + j * 16 + r16) * 32 + quad * 8);
    #pragma unroll
    for (int i = 0; i < 4; ++i)
      #pragma unroll
      for (int j = 0; j < 4; ++j)
        acc[i][j] = __builtin_amdgcn_mfma_f32_16x16x32_bf16(av[i], bv[j], acc[i][j], 0, 0, 0);
    __syncthreads();
  }

  #pragma unroll
  for (int j = 0; j < 4; ++j) {
    const int col = n0 + wn + j * 16 + r16;
    const float bj = bias[col];
    #pragma unroll
    for (int i = 0; i < 4; ++i) {
      const int mbase = m0 + wm + i * 16 + quad * 4;
      #pragma unroll
      for (int r = 0; r < 4; ++r) {
        const float val = acc[i][j][r] + bj;
        if (OUT_BF16)
          ((bf16*)Cout)[(size_t)(mbase + r) * kD + col] = __float2bfloat16(val);
        else
          ((float*)Cout)[(size_t)(mbase + r) * kD + col] = val;
      }
    }
  }
}

// -------------------------------------------------------------------------
// proj GEMM body (device, f32): proj[M,96] = Q @ Wcat + bcat. BM=64, BK=32.
// -------------------------------------------------------------------------
__device__ __forceinline__
void proj_gemm_body(char* smem, int bid,
                    const float* __restrict__ Q, const float* __restrict__ Wc,
                    const float* __restrict__ bc, float* __restrict__ proj)
{
  float (*sA)[68]  = (float (*)[68])smem;           // 8704 B
  float (*sB)[100] = (float (*)[100])(smem + 8704); // 12800 B
  const int tid = threadIdx.x;
  const int m0  = bid * 64;
  const int tm  = tid >> 4, tn = tid & 15;

  float acc[4][6] = {};

  for (int kt = 0; kt < 12; ++kt) {
    const int k0 = kt * 32;
    #pragma unroll
    for (int r = 0; r < 2; ++r) {
      const int e = tid + r * 256;
      const int m = e >> 3, kc = e & 7;
      const float4 f = *(const float4*)(Q + (size_t)(m0 + m) * kD + k0 + kc * 4);
      sA[kc * 4 + 0][m] = f.x;
      sA[kc * 4 + 1][m] = f.y;
      sA[kc * 4 + 2][m] = f.z;
      sA[kc * 4 + 3][m] = f.w;
    }
    #pragma unroll
    for (int r = 0; r < 6; ++r) {
      const int e = tid + r * 256;
      const int k = e / 48, n2 = (e % 48) * 2;
      *(float2*)(&sB[k][n2]) = *(const float2*)(Wc + (size_t)(k0 + k) * 96 + n2);
    }
    __syncthreads();
    #pragma unroll
    for (int k = 0; k < 32; ++k) {
      const float4 a  = *(const float4*)(&sA[k][tm * 4]);
      const float2 b0 = *(const float2*)(&sB[k][tn * 6]);
      const float2 b1 = *(const float2*)(&sB[k][tn * 6 + 2]);
      const float2 b2 = *(const float2*)(&sB[k][tn * 6 + 4]);
      const float av[4] = {a.x, a.y, a.z, a.w};
      const float bb[6] = {b0.x, b0.y, b1.x, b1.y, b2.x, b2.y};
      #pragma unroll
      for (int i = 0; i < 4; ++i)
        #pragma unroll
        for (int j = 0; j < 6; ++j)
          acc[i][j] += av[i] * bb[j];
    }
    __syncthreads();
  }

  #pragma unroll
  for (int j = 0; j < 6; ++j) {
    const int col = tn * 6 + j;
    const float bj = bc[col];
    #pragma unroll
    for (int i = 0; i < 4; ++i)
      proj[(size_t)(m0 + tm * 4 + i) * 96 + col] = acc[i][j] + bj;
  }
}

// -------------------------------------------------------------------------
// Fat kernel: blocks [0,512) run proj GEMM, [512,1280) run v GEMM.
// The two are independent (both only need prep outputs) — one dispatch
// lets them share the machine instead of serializing.
// -------------------------------------------------------------------------
__global__ __launch_bounds__(256)
void fat_kernel(const float* __restrict__ value, const bf16* __restrict__ Wvt,
                const float* __restrict__ bv,    bf16* __restrict__ vB,
                const float* __restrict__ Q,     const float* __restrict__ Wcat,
                const float* __restrict__ bcat,  float* __restrict__ proj)
{
  __shared__ __align__(16) char smem[21504];
  const int pb = blockIdx.x;
  if (pb < 512) {
    proj_gemm_body(smem, pb, Q, Wcat, bcat, proj);
  } else {
    mfma_gemm_body<true, true>(smem, pb - 512, value, Wvt, bv, vB);
  }
}

// standalone MFMA GEMM for the output projection
__global__ __launch_bounds__(256)
void out_gemm_kernel(const bf16* __restrict__ A, const bf16* __restrict__ Bt,
                     const float* __restrict__ bias, float* __restrict__ Cout)
{
  __shared__ __align__(16) char smem[16384];
  mfma_gemm_body<false, false>(smem, blockIdx.x, A, Bt, bias, Cout);
}

// -------------------------------------------------------------------------
// sample: 2 tokens per 256-thread block.
//  A: 192 thr load 2x96 proj -> LDS
//  B: 64 thr coords -> int4 elem-offsets + float4 bilinear wts; 16 thr softmax
//  C: 192 thr gather, each 4 dims via ushort4 loads, acc += wt*bilinear
// XCD swizzle keeps each batch's v slice in one XCD's L2.
// -------------------------------------------------------------------------
__global__ __launch_bounds__(256)
void sample_kernel(const float* __restrict__ proj, const bf16* __restrict__ v,
                   bf16* __restrict__ agg)
{
  const int b   = blockIdx.x & 7;
  const int idx = blockIdx.x >> 3;        // 0..2047
  const int t = threadIdx.x;

  __shared__ float sp[2][96];
  __shared__ int4  soff[2][32];
  __shared__ float4 sbw[2][32];
  __shared__ float swt[2][32];

  if (t < 192) {
    const int tok = t / 96, j = t % 96;
    const int token = b * kL + idx * 2 + tok;
    sp[tok][j] = proj[(size_t)token * 96 + j];
  }
  __syncthreads();

  if (t < 64) {
    const int tok = t >> 5, i = t & 31;
    const int l = idx * 2 + tok;
    const float offx = sp[tok][2 * i];
    const float offy = sp[tok][2 * i + 1];
    const float refx = (float)(l % kGW) * (1.0f / 63.0f);
    const float refy = (float)(l / kGW) * (1.0f / 63.0f);
    const float locx = fminf(fmaxf(refx + offx, 0.f), 1.f);
    const float locy = fminf(fmaxf(refy + offy, 0.f), 1.f);
    const float ph = locx * 63.0f;   // faithful: component 0 -> row coord
    const float pw = locy * 63.0f;
    const float fy = floorf(ph), fx = floorf(pw);
    const int y0 = (int)fy, x0 = (int)fx;
    const int y1 = min(y0 + 1, 63), x1 = min(x0 + 1, 63);
    const float wy = ph - fy, wx = pw - fx;
    soff[tok][i] = make_int4((y0 * kGW + x0) * kD, (y0 * kGW + x1) * kD,
                             (y1 * kGW + x0) * kD, (y1 * kGW + x1) * kD);
    sbw[tok][i] = make_float4((1.f - wy) * (1.f - wx), (1.f - wy) * wx,
                              wy * (1.f - wx),         wy * wx);
  } else if (t < 80) {
    const int u = t - 64, tok = u >> 3, hh = u & 7;
    const float* lg = &sp[tok][64 + hh * 4];
    const float m = fmaxf(fmaxf(lg[0], lg[1]), fmaxf(lg[2], lg[3]));
    float e[4], sum = 0.f;
    #pragma unroll
    for (int p = 0; p < 4; ++p) { e[p] = expf(lg[p] - m); sum += e[p]; }
    const float inv = 1.0f / sum;
    #pragma unroll
    for (int p = 0; p < 4; ++p) swt[tok][hh * 4 + p] = e[p] * inv;
  }
  __syncthreads();

  if (t < 192) {
    const int tok = t / 96, q = t % 96;
    const int h = q / 12, dg = (q % 12) * 4;     // 4 dims per thread
    const int l = idx * 2 + tok;
    const int hd = h * kHD + dg;
    const unsigned short* vb = (const unsigned short*)(v + (size_t)b * kL * kD + hd);
    float4v acc = (float4v){0.f, 0.f, 0.f, 0.f};
    #pragma unroll
    for (int p = 0; p < 4; ++p) {
      const int i = h * 4 + p;
      const int4  o  = soff[tok][i];
      const float4 bw = sbw[tok][i];
      const float wt = swt[tok][i];
      const ushort4 u0 = *(const ushort4*)(vb + o.x);
      const ushort4 u1 = *(const ushort4*)(vb + o.y);
      const ushort4 u2 = *(const ushort4*)(vb + o.z);
      const ushort4 u3 = *(const ushort4*)(vb + o.w);
      float4v s;
      s[0] = bw.x * bf16raw2f(u0.x) + bw.y * bf16raw2f(u1.x)
           + bw.z * bf16raw2f(u2.x) + bw.w * bf16raw2f(u3.x);
      s[1] = bw.x * bf16raw2f(u0.y) + bw.y * bf16raw2f(u1.y)
           + bw.z * bf16raw2f(u2.y) + bw.w * bf16raw2f(u3.y);
      s[2] = bw.x * bf16raw2f(u0.z) + bw.y * bf16raw2f(u1.z)
           + bw.z * bf16raw2f(u2.z) + bw.w * bf16raw2f(u3.z);
      s[3] = bw.x * bf16raw2f(u0.w) + bw.y * bf16raw2f(u1.w)
           + bw.z * bf16raw2f(u2.w) + bw.w * bf16raw2f(u3.w);
      #pragma unroll
      for (int d = 0; d < 4; ++d) acc[d] += wt * s[d];
    }
    ushort4 outu;
    outu.x = (unsigned short)bf16bits(acc[0]);
    outu.y = (unsigned short)bf16bits(acc[1]);
    outu.z = (unsigned short)bf16bits(acc[2]);
    outu.w = (unsigned short)bf16bits(acc[3]);
    const int token = b * kL + l;
    *(ushort4*)((unsigned short*)agg + (size_t)token * kD + hd) = outu;
  }
}

extern "C" void kernel_launch(void* const* d_in, const int* in_sizes, int n_in,
                              void* d_out, int out_size, void* d_ws, size_t ws_size,
                              hipStream_t stream)
{
  const float* query = (const float*)d_in[0];
  const float* value = (const float*)d_in[2];
  const float* Wv    = (const float*)d_in[7];
  const float* bv    = (const float*)d_in[8];
  const float* Woff  = (const float*)d_in[9];
  const float* boff  = (const float*)d_in[10];
  const float* Wwt   = (const float*)d_in[11];
  const float* bwt   = (const float*)d_in[12];
  const float* Wo    = (const float*)d_in[13];
  const float* bo    = (const float*)d_in[14];
  float* out = (float*)d_out;

  char* ws = (char*)d_ws;
  bf16*  Wvt  = (bf16*)(ws + oWvt);
  bf16*  Wot  = (bf16*)(ws + oWot);
  float* Wcat = (float*)(ws + oWcat);
  float* bcat = (float*)(ws + oBcat);
  bf16*  vB   = (bf16*)(ws + oVB);
  float* proj = (float*)(ws + oProj);
  bf16*  aggB = (bf16*)(ws + oAgg);

  const size_t prepN = nW + nW + nWcat + 96;
  prep_kernel<<<dim3((unsigned)((prepN + 255) / 256)), 256, 0, stream>>>(
      Wv, Wo, Woff, Wwt, boff, bwt, Wvt, Wot, Wcat, bcat);

  // vGEMM (768 blocks) + proj GEMM (512 blocks) in one dispatch
  fat_kernel<<<dim3(512 + 768), 256, 0, stream>>>(
      value, Wvt, bv, vB, query, Wcat, bcat, proj);

  // coords + softmax + bilinear gather -> agg (bf16)
  sample_kernel<<<dim3(kM / 2), 256, 0, stream>>>(proj, vB, aggB);

  // out = agg @ Wo + bo  (bf16 MFMA, f32 out)
  out_gemm_kernel<<<dim3((kM / 128) * 3), 256, 0, stream>>>(aggB, Wot, bo, out);
}